// Round 17
// baseline (115.016 us; speedup 1.0000x reference)
//
#include <hip/hip_runtime.h>
#include <hip/hip_bf16.h>

#define INV_SQRT2f 0.70710678118654752440f
#define BETAf 0.3f
#define OMBf  0.7f
#define LN_EPSf 1e-5f

#define B 128
#define S 1024
#define P 336
#define C 128
#define H1 32
#define H2 16

// ---------------- workspace layout (float offsets) ----------------
// ws is ~256 MiB (evidenced by the 268 MB poison fill) — we use ~55 MB.
#define WS_WHP2G  0               // bf16 A-image for k_pred, 786432 B
#define WS_EPI    262144          // float4[384]: {A13, A4, A2, -}
#define WS_BCP    296448          // 384
#define WS_H2     296832          // 128*1024*16 = 2097152
#define WS_M      2393984         // 128*336*16 = 688128
#define WS_AIMG   3426176         // bf16 conv A-image, 2359296 B (written by k_wcp)
#define WS_XIMG   4194304         // bf16 B-image of x, 32 MB = 8388608 floats
#define WS_EVP    12582912        // 128*32*128 = 524288
#define WS_SQP    13107200        // 524288
#define WS_MEAN   13631488        // 16384
#define WS_STD    13647872        // 16384
// total ~13.67M floats = 54.7 MB

typedef short  s16x8 __attribute__((ext_vector_type(8)));
typedef float  f32x4 __attribute__((ext_vector_type(4)));

// exact RNE float->bf16
__device__ __forceinline__ unsigned f2bf(float f) {
    unsigned u = __float_as_uint(f);
    return (u + 0x7fffu + ((u >> 16) & 1u)) >> 16;
}

// k_pred A-image u32 index for the pair (u=2sp, u=2sp+1) of projection row p.
__device__ __forceinline__ int whp2l_u32(int p, int sp) {
    int kt   = sp >> 4;
    int tile = kt * 2 + p / 192;
    int sub  = (p % 192) >> 4;
    int kg   = (sp & 15) >> 2;
    int m    = p & 15;
    int byte = tile * 12288 + sub * 1024 + kg * 256 + m * 16 + 4 * (sp & 3);
    return byte >> 2;
}

// ---------------------------------------------------------------------------
// k_prep: bf16 A-image (Haar-folded, BETA-scaled Whp2) + EPI + bcP
__global__ void k_prep(const float* __restrict__ Whp, const float* __restrict__ Wtp,
                       const float* __restrict__ bc,  const float* __restrict__ bhp,
                       const float* __restrict__ btp, float* __restrict__ ws)
{
    const int p = blockIdx.x;     // 0..335
    const int t = threadIdx.x;    // 256
    unsigned* img = (unsigned*)ws;
    __shared__ float red[768];
    float sw = 0.f, rw = 0.f, bp = 0.f;
    for (int sp = t; sp < 512; sp += 256) {
        float a = Whp[p * 1024 + sp];
        float d = Whp[p * 1024 + 512 + sp];
        float va = BETAf * (a + d) * INV_SQRT2f;   // u = 2sp
        float vb = BETAf * (a - d) * INV_SQRT2f;   // u = 2sp+1
        img[whp2l_u32(p, sp)] = f2bf(va) | (f2bf(vb) << 16);
        sw += a + d;
    }
    for (int s = t; s < S; s += 256) {
        float w = Wtp[p * 1024 + s];
        rw += w;
        bp += w * bc[s];
    }
    red[t] = sw; red[256 + t] = rw; red[512 + t] = bp;
    __syncthreads();
    for (int off = 128; off > 0; off >>= 1) {
        if (t < off) {
            red[t]       += red[t + off];
            red[256 + t] += red[256 + t + off];
            red[512 + t] += red[512 + t + off];
        }
        __syncthreads();
    }
    if (t == 0) {
        ws[WS_BCP + p] = red[512];
        float* e = ws + WS_EPI + p * 4;
        e[0] = BETAf * bhp[p] + OMBf * btp[p];   // A13
        e[1] = OMBf * red[256];                  // A4 = OMB*rowWtp
        e[2] = 1.f - BETAf * red[0];             // A2 = 1-BETA*sumWhp
        e[3] = 0.f;
    }
}

// ---------------------------------------------------------------------------
// MLP
__global__ void k_mlp(const float* __restrict__ xme,
                      const float* __restrict__ W1, const float* __restrict__ b1,
                      const float* __restrict__ g1, const float* __restrict__ be1,
                      const float* __restrict__ W2, const float* __restrict__ b2,
                      const float* __restrict__ g2, const float* __restrict__ be2,
                      float* __restrict__ ws)
{
    __shared__ float w1s[128], b1s[32], g1s[32], be1s[32];
    __shared__ float w2s[512], b2s[16], g2s[16], be2s[16];
    const int t = threadIdx.x;
    if (t < 128) w1s[t] = W1[t];
    if (t < 32) { b1s[t] = b1[t]; g1s[t] = g1[t]; be1s[t] = be1[t]; }
    for (int i = t; i < 512; i += 256) w2s[i] = W2[i];
    if (t < 16) { b2s[t] = b2[t]; g2s[t] = g2[t]; be2s[t] = be2[t]; }
    __syncthreads();

    const int row = blockIdx.x * 256 + t;
    float4 v = *(const float4*)(xme + (size_t)row * 4);

    float h1v[32];
    float m = 0.f;
    #pragma unroll
    for (int i = 0; i < 32; i++) {
        float a = w1s[i*4+0]*v.x + w1s[i*4+1]*v.y + w1s[i*4+2]*v.z + w1s[i*4+3]*v.w + b1s[i];
        h1v[i] = a; m += a;
    }
    m *= (1.f / 32.f);
    float var = 0.f;
    #pragma unroll
    for (int i = 0; i < 32; i++) { float d = h1v[i] - m; var += d * d; }
    var *= (1.f / 32.f);
    float rs = rsqrtf(var + LN_EPSf);
    #pragma unroll
    for (int i = 0; i < 32; i++)
        h1v[i] = fmaxf((h1v[i] - m) * rs * g1s[i] + be1s[i], 0.f);

    float h2v[16];
    float m2 = 0.f;
    #pragma unroll
    for (int g = 0; g < 16; g++) {
        float a = b2s[g];
        #pragma unroll
        for (int i = 0; i < 32; i++) a = fmaf(w2s[g * 32 + i], h1v[i], a);
        h2v[g] = a; m2 += a;
    }
    m2 *= (1.f / 16.f);
    float v2 = 0.f;
    #pragma unroll
    for (int g = 0; g < 16; g++) { float d = h2v[g] - m2; v2 += d * d; }
    v2 *= (1.f / 16.f);
    float rs2 = rsqrtf(v2 + LN_EPSf);
    float* h2o = ws + WS_H2 + (size_t)row * 16;
    #pragma unroll
    for (int g = 0; g < 16; g++)
        h2o[g] = fmaxf((h2v[g] - m2) * rs2 * g2s[g] + be2s[g], 0.f);
}

// ---------------------------------------------------------------------------
// k_xc: x (fp32) -> fragment-ordered bf16 B-image + stats partials.
// grid (b=128, kt=32), 256 thr. Image layout per (b,chalf,kt): 4096 B of
// [csub 0..3][kg 0..3][c16 0..15][e 0..7] bf16 — byte-identical to the old
// LDS Bs subtiles. Coalesced uint4 writes; stats partials per (b,kt,c).
__global__ __launch_bounds__(256) void k_xc(const float* __restrict__ x,
                                            float* __restrict__ ws)
{
    __shared__ float sev[256], ssq[256];
    const int b  = blockIdx.x;
    const int kt = blockIdx.y;
    const int t  = threadIdx.x;
    const int c  = t & 127;
    const int h  = t >> 7;            // 0,1
    const float* xb = x + (size_t)b * S * C + (size_t)(32 * kt) * C + c;
    char* ximg = (char*)(ws + WS_XIMG);

    float ev = 0.f, sq = 0.f;
    #pragma unroll
    for (int j = 0; j < 2; j++) {
        const int kg = 2 * h + j;
        const float* xs = xb + (size_t)(8 * kg) * C;
        float v[8];
        #pragma unroll
        for (int e = 0; e < 8; e++) v[e] = xs[(size_t)e * C];
        uint4 w;
        w.x = f2bf(v[0]) | (f2bf(v[1]) << 16);
        w.y = f2bf(v[2]) | (f2bf(v[3]) << 16);
        w.z = f2bf(v[4]) | (f2bf(v[5]) << 16);
        w.w = f2bf(v[6]) | (f2bf(v[7]) << 16);
        #pragma unroll
        for (int e = 0; e < 8; e++) {
            sq = fmaf(v[e], v[e], sq);
            if ((e & 1) == 0) ev += v[e];     // s = 32kt+8kg+e: even <=> e even
        }
        char* dst = ximg + ((size_t)((b * 2 + (c >> 6)) * 32 + kt)) * 4096
                  + ((((c & 63) >> 4) * 4 + kg) << 8) + ((c & 15) << 4);
        *(uint4*)dst = w;
    }
    sev[t] = ev; ssq[t] = sq;
    __syncthreads();
    if (t < 128) {
        ws[WS_EVP + ((size_t)b * 32 + kt) * 128 + t] = sev[t] + sev[t + 128];
        ws[WS_SQP + ((size_t)b * 32 + kt) * 128 + t] = ssq[t] + ssq[t + 128];
    }
}

// stats pass 2: mean/std per (b,c) from 32 partials
__global__ void k_stats2(float* __restrict__ ws)
{
    const int idx = blockIdx.x * 256 + threadIdx.x;   // b*128+c, grid 64
    const int b = idx >> 7, c = idx & 127;
    float ev = 0.f, sq = 0.f;
    for (int j = 0; j < 32; j++) {
        ev += ws[WS_EVP + ((size_t)b * 32 + j) * 128 + c];
        sq += ws[WS_SQP + ((size_t)b * 32 + j) * 128 + c];
    }
    float mean = ev * (INV_SQRT2f / 512.f);
    float var  = (sq - 1024.f * mean * mean) * (1.f / 1023.f);  // ddof=1
    ws[WS_MEAN + idx] = mean;
    ws[WS_STD + idx]  = sqrtf(var + LN_EPSf);
}

// ---------------------------------------------------------------------------
// k_wcp (MFMA, 2-deep pipeline) + FUSED repack epilogue — unchanged, passing.
__global__ __launch_bounds__(256) void k_wcp(const float* __restrict__ Wc,
                                             const float* __restrict__ Wtp,
                                             float* __restrict__ ws)
{
    __shared__ __align__(16) unsigned short Bs[2][4][4][16][8];   // 8192 B
    const int pbase = blockIdx.x * 96;
    const int n0    = blockIdx.y * 64;
    const int t     = threadIdx.x;
    const int lane  = t & 63;
    const int wid   = t >> 6;
    const int wm    = wid >> 1;          // 0,1
    const int wn    = wid & 1;           // 0,1
    const int g8    = lane >> 4;         // 0..3  (k-group)
    const int n16   = lane & 15;

    const int bn  = t & 63;
    const int bkg = t >> 6;

    int prow[3];
    #pragma unroll
    for (int fi = 0; fi < 3; fi++) {
        int pr = pbase + wm * 48 + fi * 16 + n16;
        prow[fi] = pr < P ? pr : P - 1;
    }

#define LOADB_(dst, kt) {                                                   \
    const float* xs_ = Wc + (size_t)((kt) * 32 + 8 * bkg) * 3072 + n0 + bn; \
    _Pragma("unroll")                                                       \
    for (int e_ = 0; e_ < 8; e_++) dst[e_] = xs_[(size_t)e_ * 3072]; }

#define WRITEB_(src, buf) {                                                 \
    uint4 w_;                                                               \
    w_.x = f2bf(src[0]) | (f2bf(src[1]) << 16);                             \
    w_.y = f2bf(src[2]) | (f2bf(src[3]) << 16);                             \
    w_.z = f2bf(src[4]) | (f2bf(src[5]) << 16);                             \
    w_.w = f2bf(src[6]) | (f2bf(src[7]) << 16);                             \
    *(uint4*)&Bs[buf][bn >> 4][bkg][bn & 15][0] = w_; }

#define LOADA_(dst, kt) {                                                   \
    _Pragma("unroll")                                                       \
    for (int fi_ = 0; fi_ < 3; fi_++) {                                     \
        const float* as_ = Wtp + (size_t)prow[fi_] * 1024 + (kt) * 32 + g8 * 8; \
        dst[fi_][0] = *(const float4*)(as_);                                \
        dst[fi_][1] = *(const float4*)(as_ + 4); } }

#define PACKA_(fa, src) {                                                   \
    _Pragma("unroll")                                                       \
    for (int fi_ = 0; fi_ < 3; fi_++) {                                     \
        uint4 w_;                                                           \
        w_.x = f2bf(src[fi_][0].x) | (f2bf(src[fi_][0].y) << 16);           \
        w_.y = f2bf(src[fi_][0].z) | (f2bf(src[fi_][0].w) << 16);           \
        w_.z = f2bf(src[fi_][1].x) | (f2bf(src[fi_][1].y) << 16);           \
        w_.w = f2bf(src[fi_][1].z) | (f2bf(src[fi_][1].w) << 16);           \
        fa[fi_] = *(s16x8*)&w_; } }

#define MFMA6_(buf, fa) {                                                   \
    s16x8 fb0 = *(const s16x8*)&Bs[buf][2 * wn + 0][g8][n16][0];            \
    s16x8 fb1 = *(const s16x8*)&Bs[buf][2 * wn + 1][g8][n16][0];            \
    _Pragma("unroll")                                                       \
    for (int fi_ = 0; fi_ < 3; fi_++) {                                     \
        acc[fi_][0] = __builtin_amdgcn_mfma_f32_16x16x32_bf16(fa[fi_], fb0, acc[fi_][0], 0, 0, 0); \
        acc[fi_][1] = __builtin_amdgcn_mfma_f32_16x16x32_bf16(fa[fi_], fb1, acc[fi_][1], 0, 0, 0); } }

    f32x4 acc[3][2];
    #pragma unroll
    for (int i = 0; i < 3; i++) {
        acc[i][0] = (f32x4){0.f, 0.f, 0.f, 0.f};
        acc[i][1] = (f32x4){0.f, 0.f, 0.f, 0.f};
    }

    float  b0r[8], b1r[8];
    float4 a0r[3][2], a1r[3][2];

    LOADA_(a0r, 0); LOADB_(b0r, 0);
    LOADA_(a1r, 1); LOADB_(b1r, 1);
    WRITEB_(b0r, 0);
    __syncthreads();

    for (int i = 0; i < 16; i++) {
        const int kt = 2 * i;
        {
            s16x8 fa[3];
            PACKA_(fa, a0r);
            if (kt + 2 < 32) { LOADA_(a0r, kt + 2); LOADB_(b0r, kt + 2); }
            MFMA6_(0, fa);
        }
        __syncthreads();
        WRITEB_(b1r, 1);
        __syncthreads();
        {
            s16x8 fa[3];
            PACKA_(fa, a1r);
            if (kt + 3 < 32) { LOADA_(a1r, kt + 3); LOADB_(b1r, kt + 3); }
            MFMA6_(1, fa);
        }
        __syncthreads();
        if (kt + 2 < 32) WRITEB_(b0r, 0);
        __syncthreads();
    }

#undef LOADB_
#undef WRITEB_
#undef LOADA_
#undef PACKA_
#undef MFMA6_

    // ---- fused repack epilogue: value (p, m3=i*3+k) -> bf16 A-image ----
    unsigned short* aimg16 = (unsigned short*)(ws + WS_AIMG);
    #pragma unroll
    for (int fi = 0; fi < 3; fi++) {
        #pragma unroll
        for (int q = 0; q < 2; q++) {
            const int m3 = n0 + wn * 32 + q * 16 + n16;
            const int iq = m3 / 3;
            const int k  = m3 - 3 * iq;
            const int ch = k * 32 + (iq >> 5);
            const int lh = ((iq >> 3) & 3) << 4;
            const int e  = iq & 7;
            #pragma unroll
            for (int r = 0; r < 4; r++) {
                const int p  = pbase + wm * 48 + fi * 16 + g8 * 4 + r;
                const int pf = p >> 4;
                const int l  = lh | (p & 15);
                unsigned short v = (p < P) ? (unsigned short)f2bf(acc[fi][q][r])
                                           : (unsigned short)0;
                aimg16[((size_t)(ch * 24 + pf) * 64 + l) * 8 + e] = v;
            }
        }
    }
}

// ---------------------------------------------------------------------------
// k_mconv (MFMA, 4-deep A-prefetch) — unchanged, passing.
#define HT_RS 1056            /* u16 elems per row (2112 B) */
__global__ __launch_bounds__(256) void k_mconv(float* __restrict__ ws)
{
    __shared__ unsigned short Ht[18 * HT_RS];   // 38016 B
    const int b  = blockIdx.x;
    const int pt = blockIdx.y;                  // 0..5
    const int t  = threadIdx.x;
    const int l  = t & 63;
    const int wid = t >> 6;
    const int pf = pt * 4 + wid;                // 0..23
    const int n16 = l & 15;
    const int g8  = l >> 4;

    for (int j = t; j < HT_RS; j += 256) {
        Ht[j] = 0;
        Ht[17 * HT_RS + j] = 0;
    }
    {
        const float* h2b = ws + WS_H2 + (size_t)b * 16384;
        const int s0 = t * 4;
        float v[4][16];
        #pragma unroll
        for (int rr = 0; rr < 4; rr++) {
            const float4* src = (const float4*)(h2b + (size_t)(s0 + rr) * 16);
            float4 a0 = src[0], a1 = src[1], a2 = src[2], a3 = src[3];
            v[rr][0]=a0.x; v[rr][1]=a0.y; v[rr][2]=a0.z; v[rr][3]=a0.w;
            v[rr][4]=a1.x; v[rr][5]=a1.y; v[rr][6]=a1.z; v[rr][7]=a1.w;
            v[rr][8]=a2.x; v[rr][9]=a2.y; v[rr][10]=a2.z; v[rr][11]=a2.w;
            v[rr][12]=a3.x; v[rr][13]=a3.y; v[rr][14]=a3.z; v[rr][15]=a3.w;
        }
        #pragma unroll
        for (int g = 0; g < 16; g++) {
            uint2 w;
            w.x = f2bf(v[0][g]) | (f2bf(v[1][g]) << 16);
            w.y = f2bf(v[2][g]) | (f2bf(v[3][g]) << 16);
            *(uint2*)&Ht[(g + 1) * HT_RS + s0] = w;
        }
    }
    __syncthreads();

    const uint4* ab = (const uint4*)(ws + WS_AIMG);
    const size_t lidx = (size_t)pf * 64 + l;    // lane slot; stride 1536 u4/it
    f32x4 acc = (f32x4){0.f, 0.f, 0.f, 0.f};

    uint4 nf0 = ab[lidx + (size_t)0 * 1536];
    uint4 nf1 = ab[lidx + (size_t)1 * 1536];
    uint4 nf2 = ab[lidx + (size_t)2 * 1536];
    uint4 nf3 = ab[lidx + (size_t)3 * 1536];

    for (int g = 0; g < 24; g++) {
        uint4 c0 = nf0, c1 = nf1, c2 = nf2, c3 = nf3;
        if (g < 23) {
            const size_t nb = lidx + (size_t)(g + 1) * 4 * 1536;
            nf0 = ab[nb];
            nf1 = ab[nb + 1536];
            nf2 = ab[nb + 2 * 1536];
            nf3 = ab[nb + 3 * 1536];
        }
        #pragma unroll
        for (int e = 0; e < 4; e++) {
            const int it = 4 * g + e;
            const int k  = it >> 5;
            const int kt = it & 31;
            s16x8 fb = *(const s16x8*)&Ht[(n16 + k) * HT_RS + kt * 32 + g8 * 8];
            uint4 ce = (e == 0) ? c0 : (e == 1) ? c1 : (e == 2) ? c2 : c3;
            s16x8 fa = *(s16x8*)&ce;
            acc = __builtin_amdgcn_mfma_f32_16x16x32_bf16(fa, fb, acc, 0, 0, 0);
        }
    }

    #pragma unroll
    for (int r = 0; r < 4; r++) {
        int p = pf * 16 + g8 * 4 + r;
        if (p < P)
            ws[WS_M + ((size_t)b * P + p) * 16 + n16] = acc[r] + ws[WS_BCP + p];
    }
}

// ---------------------------------------------------------------------------
// k_pred v10: BARRIER-FREE register-pipelined MFMA GEMM (k_mconv pattern).
// grid (b, 4) = {ptile, chalf}; 256 thr = 4 M-waves, wave tile 48p x 64c.
// A and B fragments are direct per-lane uint4 loads from pre-baked images
// (A: WHP2G by k_prep; B: XIMG by k_xc). No LDS, no __syncthreads, no f2bf
// in the hot loop. 3-stage rotating named prefetch (rule #20 safe).
__global__ __launch_bounds__(256, 2) void k_pred(
    const float* __restrict__ W3, const float* __restrict__ b3,
    const float* __restrict__ ws, float* __restrict__ out)
{
    const int b     = blockIdx.x;
    const int pt    = blockIdx.y;        // 0..3
    const int ptile = pt >> 1;           // 0,1 (192 p-rows each)
    const int chalf = pt & 1;            // 0,1 (64 c-cols each)
    const int t     = threadIdx.x;       // 0..255
    const int lane  = t & 63;
    const int wm    = t >> 6;            // 0..3 (4 M-waves)
    const int g8    = lane >> 4;         // 0..3  (k-group)
    const int n16   = lane & 15;

    // A image: + kt*24576 ; per-lane base
    const char* aimgc = (const char*)ws + ptile * 12288
        + (wm * 3) * 1024 + g8 * 256 + n16 * 16;
    // B image: + kt*4096 + fj*1024 ; per-lane base
    const char* bimgc = (const char*)(ws + WS_XIMG)
        + ((size_t)(b * 2 + chalf) * 32) * 4096 + (g8 << 8) + (n16 << 4);

    f32x4 acc[3][4];
    #pragma unroll
    for (int i = 0; i < 3; i++)
        #pragma unroll
        for (int j = 0; j < 4; j++) acc[i][j] = (f32x4){0.f, 0.f, 0.f, 0.f};

#define P_LOADA_(dst, kt) {                                                 \
    const char* ap_ = aimgc + (size_t)(kt) * 24576;                         \
    _Pragma("unroll")                                                       \
    for (int fi_ = 0; fi_ < 3; fi_++)                                       \
        dst[fi_] = *(const uint4*)(ap_ + fi_ * 1024); }

#define P_LOADB_(dst, kt) {                                                 \
    const char* bp_ = bimgc + (size_t)(kt) * 4096;                          \
    _Pragma("unroll")                                                       \
    for (int fj_ = 0; fj_ < 4; fj_++)                                       \
        dst[fj_] = *(const uint4*)(bp_ + fj_ * 1024); }

#define P_MFMA_(ca, cb) {                                                   \
    _Pragma("unroll")                                                       \
    for (int fi_ = 0; fi_ < 3; fi_++) {                                     \
        s16x8 fa_ = *(s16x8*)&ca[fi_];                                      \
        _Pragma("unroll")                                                   \
        for (int fj_ = 0; fj_ < 4; fj_++) {                                 \
            s16x8 fb_ = *(s16x8*)&cb[fj_];                                  \
            acc[fi_][fj_] = __builtin_amdgcn_mfma_f32_16x16x32_bf16(        \
                fa_, fb_, acc[fi_][fj_], 0, 0, 0); } } }

// One k-step with stage (SA,SB) holding tile kt; reload stage with kt+3.
#define P_STEP_(kt, SA, SB) {                                               \
    if ((kt) < 32) {                                                        \
        uint4 ca_[3], cb_[4];                                               \
        ca_[0] = SA[0]; ca_[1] = SA[1]; ca_[2] = SA[2];                     \
        cb_[0] = SB[0]; cb_[1] = SB[1]; cb_[2] = SB[2]; cb_[3] = SB[3];     \
        if ((kt) + 3 < 32) { P_LOADA_(SA, (kt) + 3); P_LOADB_(SB, (kt) + 3); } \
        P_MFMA_(ca_, cb_);                                                  \
    } }

    uint4 s0a[3], s0b[4], s1a[3], s1b[4], s2a[3], s2b[4];

    // prologue: tiles 0,1,2 in flight
    P_LOADA_(s0a, 0); P_LOADB_(s0b, 0);
    P_LOADA_(s1a, 1); P_LOADB_(s1b, 1);
    P_LOADA_(s2a, 2); P_LOADB_(s2b, 2);

    for (int i6 = 0; i6 < 6; i6++) {
        const int k0 = 6 * i6;
        P_STEP_(k0 + 0, s0a, s0b);
        P_STEP_(k0 + 1, s1a, s1b);
        P_STEP_(k0 + 2, s2a, s2b);
        P_STEP_(k0 + 3, s0a, s0b);
        P_STEP_(k0 + 4, s1a, s1b);
        P_STEP_(k0 + 5, s2a, s2b);
    }

#undef P_STEP_
#undef P_LOADA_
#undef P_LOADB_
#undef P_MFMA_

    // ---- epilogue (stats from global WS_MEAN/WS_STD) ----
    float sdv[4], mnv[4], b3v[4];
    f32x4 w3r[4][4];
    #pragma unroll
    for (int fj = 0; fj < 4; fj++) {
        int c = chalf * 64 + fj * 16 + n16;
        sdv[fj] = ws[WS_STD  + b * C + c];
        mnv[fj] = ws[WS_MEAN + b * C + c];
        b3v[fj] = b3[c];
        const f32x4* wr = (const f32x4*)(W3 + c * 16);
        #pragma unroll
        for (int q = 0; q < 4; q++) w3r[fj][q] = wr[q];
    }
    const int prow0 = ptile * 192 + wm * 48 + g8 * 4;
    #pragma unroll
    for (int fi = 0; fi < 3; fi++) {
        #pragma unroll
        for (int r = 0; r < 4; r++) {
            int p  = prow0 + fi * 16 + r;
            int pc = p < P ? p : P - 1;
            const f32x4* mrow = (const f32x4*)(ws + WS_M + ((size_t)b * P + pc) * 16);
            f32x4 m0 = mrow[0], m1 = mrow[1], m2 = mrow[2], m3 = mrow[3];
            const float* e = ws + WS_EPI + pc * 4;
            float A13 = e[0], A4 = e[1], A2 = e[2];
            #pragma unroll
            for (int fj = 0; fj < 4; fj++) {
                float s = 0.f;
                #pragma unroll
                for (int q = 0; q < 4; q++) {
                    const f32x4 mv = (q==0)?m0:(q==1)?m1:(q==2)?m2:m3;
                    s = fmaf(mv.x, w3r[fj][q].x, s);
                    s = fmaf(mv.y, w3r[fj][q].y, s);
                    s = fmaf(mv.z, w3r[fj][q].z, s);
                    s = fmaf(mv.w, w3r[fj][q].w, s);
                }
                float res = acc[fi][fj][r]
                          + sdv[fj] * (OMBf * s + A13 + A4 * b3v[fj])
                          + A2 * mnv[fj];
                if (p < P)
                    out[((size_t)b * P + p) * C + chalf * 64 + fj * 16 + n16] = res;
            }
        }
    }
}

// ---------------------------------------------------------------------------
extern "C" void kernel_launch(void* const* d_in, const int* in_sizes, int n_in,
                              void* d_out, int out_size, void* d_ws, size_t ws_size,
                              hipStream_t stream)
{
    const float* x    = (const float*)d_in[0];
    const float* xme  = (const float*)d_in[1];
    const float* W1   = (const float*)d_in[4];
    const float* b1   = (const float*)d_in[5];
    const float* g1   = (const float*)d_in[6];
    const float* be1  = (const float*)d_in[7];
    const float* W2   = (const float*)d_in[8];
    const float* b2   = (const float*)d_in[9];
    const float* g2   = (const float*)d_in[10];
    const float* be2  = (const float*)d_in[11];
    const float* Wc   = (const float*)d_in[12];
    const float* bc   = (const float*)d_in[13];
    const float* W3   = (const float*)d_in[14];
    const float* b3   = (const float*)d_in[15];
    const float* Wtp  = (const float*)d_in[16];
    const float* btp  = (const float*)d_in[17];
    const float* Whp  = (const float*)d_in[18];
    const float* bhp  = (const float*)d_in[19];
    float* ws  = (float*)d_ws;
    float* out = (float*)d_out;

    k_prep  <<<dim3(P),      dim3(256), 0, stream>>>(Whp, Wtp, bc, bhp, btp, ws);
    k_mlp   <<<dim3(512),    dim3(256), 0, stream>>>(xme, W1, b1, g1, be1,
                                                     W2, b2, g2, be2, ws);
    k_xc    <<<dim3(B, 32),  dim3(256), 0, stream>>>(x, ws);
    k_stats2<<<dim3(64),     dim3(256), 0, stream>>>(ws);
    k_wcp   <<<dim3(4, 48),  dim3(256), 0, stream>>>(Wc, Wtp, ws);
    k_mconv <<<dim3(B, 6),   dim3(256), 0, stream>>>(ws);
    k_pred  <<<dim3(B, 4),   dim3(256), 0, stream>>>(W3, b3, ws, out);
}

// Round 18
// 96.163 us; speedup vs baseline: 1.1961x; 1.1961x over previous
//
#include <hip/hip_runtime.h>
#include <hip/hip_bf16.h>

#define INV_SQRT2f 0.70710678118654752440f
#define BETAf 0.3f
#define OMBf  0.7f
#define LN_EPSf 1e-5f

#define B 128
#define S 1024
#define P 336
#define C 128
#define H1 32
#define H2 16

// ---------------- workspace layout (float offsets) ----------------
#define WS_WHP2G  0               // bf16 A-image for k_pred, 786432 B
#define WS_EPI    262144          // float4[384]: {A13, A4, A2, -}
#define WS_BCP    296448          // 384
#define WS_H2     296832          // 128*1024*16 = 2097152
#define WS_M      2393984         // 128*336*16 = 688128
#define WS_AIMG   3426176         // bf16 conv A-image, 2359296 B (written by k_wcp)
// total < 4245376 floats = 16.98 MB

typedef short  s16x8 __attribute__((ext_vector_type(8)));
typedef float  f32x4 __attribute__((ext_vector_type(4)));

// exact RNE float->bf16
__device__ __forceinline__ unsigned f2bf(float f) {
    unsigned u = __float_as_uint(f);
    return (u + 0x7fffu + ((u >> 16) & 1u)) >> 16;
}

// k_pred A-image u32 index for the pair (u=2sp, u=2sp+1) of projection row p.
__device__ __forceinline__ int whp2l_u32(int p, int sp) {
    int kt   = sp >> 4;
    int tile = kt * 2 + p / 192;
    int sub  = (p % 192) >> 4;
    int kg   = (sp & 15) >> 2;
    int m    = p & 15;
    int byte = tile * 12288 + sub * 1024 + kg * 256 + m * 16 + 4 * (sp & 3);
    return byte >> 2;
}

// ---------------------------------------------------------------------------
// k_prep: bf16 A-image (Haar-folded, BETA-scaled Whp2) + EPI + bcP
__global__ void k_prep(const float* __restrict__ Whp, const float* __restrict__ Wtp,
                       const float* __restrict__ bc,  const float* __restrict__ bhp,
                       const float* __restrict__ btp, float* __restrict__ ws)
{
    const int p = blockIdx.x;     // 0..335
    const int t = threadIdx.x;    // 256
    unsigned* img = (unsigned*)ws;
    __shared__ float red[768];
    float sw = 0.f, rw = 0.f, bp = 0.f;
    for (int sp = t; sp < 512; sp += 256) {
        float a = Whp[p * 1024 + sp];
        float d = Whp[p * 1024 + 512 + sp];
        float va = BETAf * (a + d) * INV_SQRT2f;   // u = 2sp
        float vb = BETAf * (a - d) * INV_SQRT2f;   // u = 2sp+1
        img[whp2l_u32(p, sp)] = f2bf(va) | (f2bf(vb) << 16);
        sw += a + d;
    }
    for (int s = t; s < S; s += 256) {
        float w = Wtp[p * 1024 + s];
        rw += w;
        bp += w * bc[s];
    }
    red[t] = sw; red[256 + t] = rw; red[512 + t] = bp;
    __syncthreads();
    for (int off = 128; off > 0; off >>= 1) {
        if (t < off) {
            red[t]       += red[t + off];
            red[256 + t] += red[256 + t + off];
            red[512 + t] += red[512 + t + off];
        }
        __syncthreads();
    }
    if (t == 0) {
        ws[WS_BCP + p] = red[512];
        float* e = ws + WS_EPI + p * 4;
        e[0] = BETAf * bhp[p] + OMBf * btp[p];   // A13
        e[1] = OMBf * red[256];                  // A4 = OMB*rowWtp
        e[2] = 1.f - BETAf * red[0];             // A2 = 1-BETA*sumWhp
        e[3] = 0.f;
    }
}

// ---------------------------------------------------------------------------
// MLP
__global__ void k_mlp(const float* __restrict__ xme,
                      const float* __restrict__ W1, const float* __restrict__ b1,
                      const float* __restrict__ g1, const float* __restrict__ be1,
                      const float* __restrict__ W2, const float* __restrict__ b2,
                      const float* __restrict__ g2, const float* __restrict__ be2,
                      float* __restrict__ ws)
{
    __shared__ float w1s[128], b1s[32], g1s[32], be1s[32];
    __shared__ float w2s[512], b2s[16], g2s[16], be2s[16];
    const int t = threadIdx.x;
    if (t < 128) w1s[t] = W1[t];
    if (t < 32) { b1s[t] = b1[t]; g1s[t] = g1[t]; be1s[t] = be1[t]; }
    for (int i = t; i < 512; i += 256) w2s[i] = W2[i];
    if (t < 16) { b2s[t] = b2[t]; g2s[t] = g2[t]; be2s[t] = be2[t]; }
    __syncthreads();

    const int row = blockIdx.x * 256 + t;
    float4 v = *(const float4*)(xme + (size_t)row * 4);

    float h1v[32];
    float m = 0.f;
    #pragma unroll
    for (int i = 0; i < 32; i++) {
        float a = w1s[i*4+0]*v.x + w1s[i*4+1]*v.y + w1s[i*4+2]*v.z + w1s[i*4+3]*v.w + b1s[i];
        h1v[i] = a; m += a;
    }
    m *= (1.f / 32.f);
    float var = 0.f;
    #pragma unroll
    for (int i = 0; i < 32; i++) { float d = h1v[i] - m; var += d * d; }
    var *= (1.f / 32.f);
    float rs = rsqrtf(var + LN_EPSf);
    #pragma unroll
    for (int i = 0; i < 32; i++)
        h1v[i] = fmaxf((h1v[i] - m) * rs * g1s[i] + be1s[i], 0.f);

    float h2v[16];
    float m2 = 0.f;
    #pragma unroll
    for (int g = 0; g < 16; g++) {
        float a = b2s[g];
        #pragma unroll
        for (int i = 0; i < 32; i++) a = fmaf(w2s[g * 32 + i], h1v[i], a);
        h2v[g] = a; m2 += a;
    }
    m2 *= (1.f / 16.f);
    float v2 = 0.f;
    #pragma unroll
    for (int g = 0; g < 16; g++) { float d = h2v[g] - m2; v2 += d * d; }
    v2 *= (1.f / 16.f);
    float rs2 = rsqrtf(v2 + LN_EPSf);
    float* h2o = ws + WS_H2 + (size_t)row * 16;
    #pragma unroll
    for (int g = 0; g < 16; g++)
        h2o[g] = fmaxf((h2v[g] - m2) * rs2 * g2s[g] + be2s[g], 0.f);
}

// ---------------------------------------------------------------------------
// k_wcp (MFMA, 2-deep pipeline) + FUSED repack epilogue — unchanged, passing.
__global__ __launch_bounds__(256) void k_wcp(const float* __restrict__ Wc,
                                             const float* __restrict__ Wtp,
                                             float* __restrict__ ws)
{
    __shared__ __align__(16) unsigned short Bs[2][4][4][16][8];   // 8192 B
    const int pbase = blockIdx.x * 96;
    const int n0    = blockIdx.y * 64;
    const int t     = threadIdx.x;
    const int lane  = t & 63;
    const int wid   = t >> 6;
    const int wm    = wid >> 1;          // 0,1
    const int wn    = wid & 1;           // 0,1
    const int g8    = lane >> 4;         // 0..3  (k-group)
    const int n16   = lane & 15;

    const int bn  = t & 63;
    const int bkg = t >> 6;

    int prow[3];
    #pragma unroll
    for (int fi = 0; fi < 3; fi++) {
        int pr = pbase + wm * 48 + fi * 16 + n16;
        prow[fi] = pr < P ? pr : P - 1;
    }

#define LOADB_(dst, kt) {                                                   \
    const float* xs_ = Wc + (size_t)((kt) * 32 + 8 * bkg) * 3072 + n0 + bn; \
    _Pragma("unroll")                                                       \
    for (int e_ = 0; e_ < 8; e_++) dst[e_] = xs_[(size_t)e_ * 3072]; }

#define WRITEB_(src, buf) {                                                 \
    uint4 w_;                                                               \
    w_.x = f2bf(src[0]) | (f2bf(src[1]) << 16);                             \
    w_.y = f2bf(src[2]) | (f2bf(src[3]) << 16);                             \
    w_.z = f2bf(src[4]) | (f2bf(src[5]) << 16);                             \
    w_.w = f2bf(src[6]) | (f2bf(src[7]) << 16);                             \
    *(uint4*)&Bs[buf][bn >> 4][bkg][bn & 15][0] = w_; }

#define LOADA_(dst, kt) {                                                   \
    _Pragma("unroll")                                                       \
    for (int fi_ = 0; fi_ < 3; fi_++) {                                     \
        const float* as_ = Wtp + (size_t)prow[fi_] * 1024 + (kt) * 32 + g8 * 8; \
        dst[fi_][0] = *(const float4*)(as_);                                \
        dst[fi_][1] = *(const float4*)(as_ + 4); } }

#define PACKA_(fa, src) {                                                   \
    _Pragma("unroll")                                                       \
    for (int fi_ = 0; fi_ < 3; fi_++) {                                     \
        uint4 w_;                                                           \
        w_.x = f2bf(src[fi_][0].x) | (f2bf(src[fi_][0].y) << 16);           \
        w_.y = f2bf(src[fi_][0].z) | (f2bf(src[fi_][0].w) << 16);           \
        w_.z = f2bf(src[fi_][1].x) | (f2bf(src[fi_][1].y) << 16);           \
        w_.w = f2bf(src[fi_][1].z) | (f2bf(src[fi_][1].w) << 16);           \
        fa[fi_] = *(s16x8*)&w_; } }

#define MFMA6_(buf, fa) {                                                   \
    s16x8 fb0 = *(const s16x8*)&Bs[buf][2 * wn + 0][g8][n16][0];            \
    s16x8 fb1 = *(const s16x8*)&Bs[buf][2 * wn + 1][g8][n16][0];            \
    _Pragma("unroll")                                                       \
    for (int fi_ = 0; fi_ < 3; fi_++) {                                     \
        acc[fi_][0] = __builtin_amdgcn_mfma_f32_16x16x32_bf16(fa[fi_], fb0, acc[fi_][0], 0, 0, 0); \
        acc[fi_][1] = __builtin_amdgcn_mfma_f32_16x16x32_bf16(fa[fi_], fb1, acc[fi_][1], 0, 0, 0); } }

    f32x4 acc[3][2];
    #pragma unroll
    for (int i = 0; i < 3; i++) {
        acc[i][0] = (f32x4){0.f, 0.f, 0.f, 0.f};
        acc[i][1] = (f32x4){0.f, 0.f, 0.f, 0.f};
    }

    float  b0r[8], b1r[8];
    float4 a0r[3][2], a1r[3][2];

    LOADA_(a0r, 0); LOADB_(b0r, 0);
    LOADA_(a1r, 1); LOADB_(b1r, 1);
    WRITEB_(b0r, 0);
    __syncthreads();

    for (int i = 0; i < 16; i++) {
        const int kt = 2 * i;
        {
            s16x8 fa[3];
            PACKA_(fa, a0r);
            if (kt + 2 < 32) { LOADA_(a0r, kt + 2); LOADB_(b0r, kt + 2); }
            MFMA6_(0, fa);
        }
        __syncthreads();
        WRITEB_(b1r, 1);
        __syncthreads();
        {
            s16x8 fa[3];
            PACKA_(fa, a1r);
            if (kt + 3 < 32) { LOADA_(a1r, kt + 3); LOADB_(b1r, kt + 3); }
            MFMA6_(1, fa);
        }
        __syncthreads();
        if (kt + 2 < 32) WRITEB_(b0r, 0);
        __syncthreads();
    }

#undef LOADB_
#undef WRITEB_
#undef LOADA_
#undef PACKA_
#undef MFMA6_

    // ---- fused repack epilogue: value (p, m3=i*3+k) -> bf16 A-image ----
    unsigned short* aimg16 = (unsigned short*)(ws + WS_AIMG);
    #pragma unroll
    for (int fi = 0; fi < 3; fi++) {
        #pragma unroll
        for (int q = 0; q < 2; q++) {
            const int m3 = n0 + wn * 32 + q * 16 + n16;
            const int iq = m3 / 3;
            const int k  = m3 - 3 * iq;
            const int ch = k * 32 + (iq >> 5);
            const int lh = ((iq >> 3) & 3) << 4;
            const int e  = iq & 7;
            #pragma unroll
            for (int r = 0; r < 4; r++) {
                const int p  = pbase + wm * 48 + fi * 16 + g8 * 4 + r;
                const int pf = p >> 4;
                const int l  = lh | (p & 15);
                unsigned short v = (p < P) ? (unsigned short)f2bf(acc[fi][q][r])
                                           : (unsigned short)0;
                aimg16[((size_t)(ch * 24 + pf) * 64 + l) * 8 + e] = v;
            }
        }
    }
}

// ---------------------------------------------------------------------------
// k_mconv (MFMA, 4-deep A-prefetch) — unchanged, passing.
#define HT_RS 1056            /* u16 elems per row (2112 B) */
__global__ __launch_bounds__(256) void k_mconv(float* __restrict__ ws)
{
    __shared__ unsigned short Ht[18 * HT_RS];   // 38016 B
    const int b  = blockIdx.x;
    const int pt = blockIdx.y;                  // 0..5
    const int t  = threadIdx.x;
    const int l  = t & 63;
    const int wid = t >> 6;
    const int pf = pt * 4 + wid;                // 0..23
    const int n16 = l & 15;
    const int g8  = l >> 4;

    for (int j = t; j < HT_RS; j += 256) {
        Ht[j] = 0;
        Ht[17 * HT_RS + j] = 0;
    }
    {
        const float* h2b = ws + WS_H2 + (size_t)b * 16384;
        const int s0 = t * 4;
        float v[4][16];
        #pragma unroll
        for (int rr = 0; rr < 4; rr++) {
            const float4* src = (const float4*)(h2b + (size_t)(s0 + rr) * 16);
            float4 a0 = src[0], a1 = src[1], a2 = src[2], a3 = src[3];
            v[rr][0]=a0.x; v[rr][1]=a0.y; v[rr][2]=a0.z; v[rr][3]=a0.w;
            v[rr][4]=a1.x; v[rr][5]=a1.y; v[rr][6]=a1.z; v[rr][7]=a1.w;
            v[rr][8]=a2.x; v[rr][9]=a2.y; v[rr][10]=a2.z; v[rr][11]=a2.w;
            v[rr][12]=a3.x; v[rr][13]=a3.y; v[rr][14]=a3.z; v[rr][15]=a3.w;
        }
        #pragma unroll
        for (int g = 0; g < 16; g++) {
            uint2 w;
            w.x = f2bf(v[0][g]) | (f2bf(v[1][g]) << 16);
            w.y = f2bf(v[2][g]) | (f2bf(v[3][g]) << 16);
            *(uint2*)&Ht[(g + 1) * HT_RS + s0] = w;
        }
    }
    __syncthreads();

    const uint4* ab = (const uint4*)(ws + WS_AIMG);
    const size_t lidx = (size_t)pf * 64 + l;    // lane slot; stride 1536 u4/it
    f32x4 acc = (f32x4){0.f, 0.f, 0.f, 0.f};

    uint4 nf0 = ab[lidx + (size_t)0 * 1536];
    uint4 nf1 = ab[lidx + (size_t)1 * 1536];
    uint4 nf2 = ab[lidx + (size_t)2 * 1536];
    uint4 nf3 = ab[lidx + (size_t)3 * 1536];

    for (int g = 0; g < 24; g++) {
        uint4 c0 = nf0, c1 = nf1, c2 = nf2, c3 = nf3;
        if (g < 23) {
            const size_t nb = lidx + (size_t)(g + 1) * 4 * 1536;
            nf0 = ab[nb];
            nf1 = ab[nb + 1536];
            nf2 = ab[nb + 2 * 1536];
            nf3 = ab[nb + 3 * 1536];
        }
        #pragma unroll
        for (int e = 0; e < 4; e++) {
            const int it = 4 * g + e;
            const int k  = it >> 5;
            const int kt = it & 31;
            s16x8 fb = *(const s16x8*)&Ht[(n16 + k) * HT_RS + kt * 32 + g8 * 8];
            uint4 ce = (e == 0) ? c0 : (e == 1) ? c1 : (e == 2) ? c2 : c3;
            s16x8 fa = *(s16x8*)&ce;
            acc = __builtin_amdgcn_mfma_f32_16x16x32_bf16(fa, fb, acc, 0, 0, 0);
        }
    }

    #pragma unroll
    for (int r = 0; r < 4; r++) {
        int p = pf * 16 + g8 * 4 + r;
        if (p < P)
            ws[WS_M + ((size_t)b * P + p) * 16 + n16] = acc[r] + ws[WS_BCP + p];
    }
}

// ---------------------------------------------------------------------------
// k_pred (R14 best-measured): MFMA bf16 GEMM + fused stats + fused epilogue.
// N-split: block = 192p x 64c, 256 threads (4 waves = 4M x 1N), grid (b, 4);
// counted-wait barrier (lgkmcnt-only + raw s_barrier).
#define P_BAR_() { asm volatile("s_waitcnt lgkmcnt(0)" ::: "memory");       \
                   __builtin_amdgcn_s_barrier(); }

__global__ __launch_bounds__(256, 2) void k_pred(
    const float* __restrict__ x,
    const float* __restrict__ W3, const float* __restrict__ b3,
    const float* __restrict__ ws, float* __restrict__ out)
{
    __shared__ __align__(16) unsigned short Bs[2][4][4][16][8];   // 8192 B
    __shared__ float sev[256], ssq[256], smean[64], sstd[64];
    const int b     = blockIdx.x;
    const int pt    = blockIdx.y;        // 0..3
    const int ptile = pt >> 1;           // 0,1 (192 p-rows each)
    const int chalf = pt & 1;            // 0,1 (64 c-cols each)
    const int t     = threadIdx.x;       // 0..255
    const int lane  = t & 63;
    const int wm    = t >> 6;            // 0..3 (4 M-waves)
    const int g8    = lane >> 4;         // 0..3  (k-group)
    const int n16   = lane & 15;

    const int sc  = t & 63;              // staging column (local)
    const int skg = t >> 6;              // staging k-group 0..3

    const float* xb = x + (size_t)b * S * C + chalf * 64;
    // A image: tile (kt*2 + ptile)*12288 B; sub = wm*3 + fi
    const char* aimgc = (const char*)ws + ptile * 12288
        + (wm * 3) * 1024 + g8 * 256 + n16 * 16;

    f32x4 acc[3][4];
    #pragma unroll
    for (int i = 0; i < 3; i++)
        #pragma unroll
        for (int j = 0; j < 4; j++) acc[i][j] = (f32x4){0.f, 0.f, 0.f, 0.f};

    float ev_acc = 0.f, sq_acc = 0.f;    // per-thread stats partials (col sc)

#define P_LOADB_(dst, kt) {                                                 \
    const float* xs_ = xb + (size_t)(32 * (kt) + 8 * skg) * C + sc;         \
    _Pragma("unroll")                                                       \
    for (int e_ = 0; e_ < 8; e_++) dst[e_] = xs_[(size_t)e_ * C]; }

#define P_WRITEB_(src, buf) {                                               \
    uint4 w_;                                                               \
    w_.x = f2bf(src[0]) | (f2bf(src[1]) << 16);                             \
    w_.y = f2bf(src[2]) | (f2bf(src[3]) << 16);                             \
    w_.z = f2bf(src[4]) | (f2bf(src[5]) << 16);                             \
    w_.w = f2bf(src[6]) | (f2bf(src[7]) << 16);                             \
    *(uint4*)&Bs[buf][sc >> 4][skg][sc & 15][0] = w_;                       \
    _Pragma("unroll")                                                       \
    for (int e_ = 0; e_ < 8; e_++) {                                        \
        float v_ = src[e_];                                                 \
        sq_acc = fmaf(v_, v_, sq_acc);                                      \
        if ((e_ & 1) == 0) ev_acc += v_;   /* s=32kt+8skg+e: even<=>e even */ \
    } }

#define P_LOADA_(dst, kt) {                                                 \
    const char* ap_ = aimgc + (size_t)(kt) * 24576;                         \
    _Pragma("unroll")                                                       \
    for (int fi_ = 0; fi_ < 3; fi_++)                                       \
        dst[fi_] = *(const uint4*)(ap_ + fi_ * 1024); }

#define P_MFMA_(buf, au) {                                                  \
    s16x8 fb0 = *(const s16x8*)&Bs[buf][0][g8][n16][0];                     \
    s16x8 fb1 = *(const s16x8*)&Bs[buf][1][g8][n16][0];                     \
    s16x8 fb2 = *(const s16x8*)&Bs[buf][2][g8][n16][0];                     \
    s16x8 fb3 = *(const s16x8*)&Bs[buf][3][g8][n16][0];                     \
    _Pragma("unroll")                                                       \
    for (int fi_ = 0; fi_ < 3; fi_++) {                                     \
        s16x8 fa_ = *(s16x8*)&au[fi_];                                      \
        acc[fi_][0] = __builtin_amdgcn_mfma_f32_16x16x32_bf16(fa_, fb0, acc[fi_][0], 0, 0, 0); \
        acc[fi_][1] = __builtin_amdgcn_mfma_f32_16x16x32_bf16(fa_, fb1, acc[fi_][1], 0, 0, 0); \
        acc[fi_][2] = __builtin_amdgcn_mfma_f32_16x16x32_bf16(fa_, fb2, acc[fi_][2], 0, 0, 0); \
        acc[fi_][3] = __builtin_amdgcn_mfma_f32_16x16x32_bf16(fa_, fb3, acc[fi_][3], 0, 0, 0); } }

    float b0r[8], b1r[8];     // R0 = even tiles, R1 = odd tiles
    uint4 a0u[3], a1u[3];

    // prologue: issue tiles 0,1; write tile 0 -> buf0
    P_LOADB_(b0r, 0); P_LOADB_(b1r, 1);
    P_LOADA_(a0u, 0); P_LOADA_(a1u, 1);
    P_WRITEB_(b0r, 0);
    P_BAR_();

    for (int i = 0; i < 16; i++) {
        const int kt = 2 * i;
        // even step kt: MFMA(buf0) || write tile kt+1 -> buf1
        {
            uint4 au[3];
            #pragma unroll
            for (int fi = 0; fi < 3; fi++) au[fi] = a0u[fi];   // A(kt), issued kt-2
            if (kt + 2 < 32) { P_LOADA_(a0u, kt + 2); P_LOADB_(b0r, kt + 2); }
            P_MFMA_(0, au);
            P_WRITEB_(b1r, 1);            // tile kt+1 (loads issued >=1 iter ago)
            P_BAR_();
        }
        // odd step kt+1: MFMA(buf1) || write tile kt+2 -> buf0
        {
            const int kt1 = kt + 1;
            uint4 au[3];
            #pragma unroll
            for (int fi = 0; fi < 3; fi++) au[fi] = a1u[fi];   // A(kt1)
            if (kt1 + 2 < 32) { P_LOADA_(a1u, kt1 + 2); P_LOADB_(b1r, kt1 + 2); }
            P_MFMA_(1, au);
            if (kt1 < 31) P_WRITEB_(b0r, 0);   // tile kt1+1
            P_BAR_();
        }
    }

#undef P_LOADB_
#undef P_WRITEB_
#undef P_LOADA_
#undef P_MFMA_

    // ---- in-block stats reduction (4 skg-groups share column sc) ----
    sev[t] = ev_acc; ssq[t] = sq_acc;
    __syncthreads();
    if (t < 64) {
        float ev = sev[t] + sev[t + 64] + sev[t + 128] + sev[t + 192];
        float sq = ssq[t] + ssq[t + 64] + ssq[t + 128] + ssq[t + 192];
        float mean = ev * (INV_SQRT2f / 512.f);
        float var  = (sq - 1024.f * mean * mean) * (1.f / 1023.f);  // ddof=1
        smean[t] = mean;
        sstd[t]  = sqrtf(var + LN_EPSf);
    }
    __syncthreads();

    // ---- epilogue ----
    float sdv[4], mnv[4], b3v[4];
    f32x4 w3r[4][4];
    #pragma unroll
    for (int fj = 0; fj < 4; fj++) {
        int cl = fj * 16 + n16;            // local col 0..63
        int c  = chalf * 64 + cl;          // global col
        sdv[fj] = sstd[cl];
        mnv[fj] = smean[cl];
        b3v[fj] = b3[c];
        const f32x4* wr = (const f32x4*)(W3 + c * 16);
        #pragma unroll
        for (int q = 0; q < 4; q++) w3r[fj][q] = wr[q];
    }
    const int prow0 = ptile * 192 + wm * 48 + g8 * 4;
    #pragma unroll
    for (int fi = 0; fi < 3; fi++) {
        #pragma unroll
        for (int r = 0; r < 4; r++) {
            int p  = prow0 + fi * 16 + r;
            int pc = p < P ? p : P - 1;
            const f32x4* mrow = (const f32x4*)(ws + WS_M + ((size_t)b * P + pc) * 16);
            f32x4 m0 = mrow[0], m1 = mrow[1], m2 = mrow[2], m3 = mrow[3];
            const float* e = ws + WS_EPI + pc * 4;
            float A13 = e[0], A4 = e[1], A2 = e[2];
            #pragma unroll
            for (int fj = 0; fj < 4; fj++) {
                float s = 0.f;
                #pragma unroll
                for (int q = 0; q < 4; q++) {
                    const f32x4 mv = (q==0)?m0:(q==1)?m1:(q==2)?m2:m3;
                    s = fmaf(mv.x, w3r[fj][q].x, s);
                    s = fmaf(mv.y, w3r[fj][q].y, s);
                    s = fmaf(mv.z, w3r[fj][q].z, s);
                    s = fmaf(mv.w, w3r[fj][q].w, s);
                }
                float res = acc[fi][fj][r]
                          + sdv[fj] * (OMBf * s + A13 + A4 * b3v[fj])
                          + A2 * mnv[fj];
                if (p < P)
                    out[((size_t)b * P + p) * C + chalf * 64 + fj * 16 + n16] = res;
            }
        }
    }
}

// ---------------------------------------------------------------------------
extern "C" void kernel_launch(void* const* d_in, const int* in_sizes, int n_in,
                              void* d_out, int out_size, void* d_ws, size_t ws_size,
                              hipStream_t stream)
{
    const float* x    = (const float*)d_in[0];
    const float* xme  = (const float*)d_in[1];
    const float* W1   = (const float*)d_in[4];
    const float* b1   = (const float*)d_in[5];
    const float* g1   = (const float*)d_in[6];
    const float* be1  = (const float*)d_in[7];
    const float* W2   = (const float*)d_in[8];
    const float* b2   = (const float*)d_in[9];
    const float* g2   = (const float*)d_in[10];
    const float* be2  = (const float*)d_in[11];
    const float* Wc   = (const float*)d_in[12];
    const float* bc   = (const float*)d_in[13];
    const float* W3   = (const float*)d_in[14];
    const float* b3   = (const float*)d_in[15];
    const float* Wtp  = (const float*)d_in[16];
    const float* btp  = (const float*)d_in[17];
    const float* Whp  = (const float*)d_in[18];
    const float* bhp  = (const float*)d_in[19];
    float* ws  = (float*)d_ws;
    float* out = (float*)d_out;

    k_prep  <<<dim3(P),      dim3(256), 0, stream>>>(Whp, Wtp, bc, bhp, btp, ws);
    k_mlp   <<<dim3(512),    dim3(256), 0, stream>>>(xme, W1, b1, g1, be1,
                                                     W2, b2, g2, be2, ws);
    k_wcp   <<<dim3(4, 48),  dim3(256), 0, stream>>>(Wc, Wtp, ws);
    k_mconv <<<dim3(B, 6),   dim3(256), 0, stream>>>(ws);
    k_pred  <<<dim3(B, 4),   dim3(256), 0, stream>>>(x, W3, b3, ws, out);
}

// Round 20
// 95.837 us; speedup vs baseline: 1.2001x; 1.0034x over previous
//
#include <hip/hip_runtime.h>
#include <hip/hip_bf16.h>

#define INV_SQRT2f 0.70710678118654752440f
#define BETAf 0.3f
#define OMBf  0.7f
#define LN_EPSf 1e-5f

#define B 128
#define S 1024
#define P 336
#define C 128
#define H1 32
#define H2 16

// ---------------- workspace layout (float offsets) ----------------
#define WS_WHP2G  0               // bf16 A-image for k_pred, 786432 B
#define WS_EPI    262144          // float4[384]: {A13, A4, A2, -}
#define WS_BCP    296448          // 384
#define WS_H2     296832          // 128*1024*16 = 2097152
#define WS_M      2393984         // 128*336*16 = 688128
#define WS_AIMG   3426176         // bf16 conv A-image, 2359296 B (written by k_wcp)
// total < 4245376 floats = 16.98 MB

typedef short  s16x8 __attribute__((ext_vector_type(8)));
typedef float  f32x4 __attribute__((ext_vector_type(4)));

// exact RNE float->bf16
__device__ __forceinline__ unsigned f2bf(float f) {
    unsigned u = __float_as_uint(f);
    return (u + 0x7fffu + ((u >> 16) & 1u)) >> 16;
}

// k_pred A-image u32 index for the pair (u=2sp, u=2sp+1) of projection row p.
__device__ __forceinline__ int whp2l_u32(int p, int sp) {
    int kt   = sp >> 4;
    int tile = kt * 2 + p / 192;
    int sub  = (p % 192) >> 4;
    int kg   = (sp & 15) >> 2;
    int m    = p & 15;
    int byte = tile * 12288 + sub * 1024 + kg * 256 + m * 16 + 4 * (sp & 3);
    return byte >> 2;
}

// ---------------------------------------------------------------------------
// k_prep: bf16 A-image (Haar-folded, BETA-scaled Whp2) + EPI + bcP
__global__ void k_prep(const float* __restrict__ Whp, const float* __restrict__ Wtp,
                       const float* __restrict__ bc,  const float* __restrict__ bhp,
                       const float* __restrict__ btp, float* __restrict__ ws)
{
    const int p = blockIdx.x;     // 0..335
    const int t = threadIdx.x;    // 256
    unsigned* img = (unsigned*)ws;
    __shared__ float red[768];
    float sw = 0.f, rw = 0.f, bp = 0.f;
    for (int sp = t; sp < 512; sp += 256) {
        float a = Whp[p * 1024 + sp];
        float d = Whp[p * 1024 + 512 + sp];
        float va = BETAf * (a + d) * INV_SQRT2f;   // u = 2sp
        float vb = BETAf * (a - d) * INV_SQRT2f;   // u = 2sp+1
        img[whp2l_u32(p, sp)] = f2bf(va) | (f2bf(vb) << 16);
        sw += a + d;
    }
    for (int s = t; s < S; s += 256) {
        float w = Wtp[p * 1024 + s];
        rw += w;
        bp += w * bc[s];
    }
    red[t] = sw; red[256 + t] = rw; red[512 + t] = bp;
    __syncthreads();
    for (int off = 128; off > 0; off >>= 1) {
        if (t < off) {
            red[t]       += red[t + off];
            red[256 + t] += red[256 + t + off];
            red[512 + t] += red[512 + t + off];
        }
        __syncthreads();
    }
    if (t == 0) {
        ws[WS_BCP + p] = red[512];
        float* e = ws + WS_EPI + p * 4;
        e[0] = BETAf * bhp[p] + OMBf * btp[p];   // A13
        e[1] = OMBf * red[256];                  // A4 = OMB*rowWtp
        e[2] = 1.f - BETAf * red[0];             // A2 = 1-BETA*sumWhp
        e[3] = 0.f;
    }
}

// ---------------------------------------------------------------------------
// MLP
__global__ void k_mlp(const float* __restrict__ xme,
                      const float* __restrict__ W1, const float* __restrict__ b1,
                      const float* __restrict__ g1, const float* __restrict__ be1,
                      const float* __restrict__ W2, const float* __restrict__ b2,
                      const float* __restrict__ g2, const float* __restrict__ be2,
                      float* __restrict__ ws)
{
    __shared__ float w1s[128], b1s[32], g1s[32], be1s[32];
    __shared__ float w2s[512], b2s[16], g2s[16], be2s[16];
    const int t = threadIdx.x;
    if (t < 128) w1s[t] = W1[t];
    if (t < 32) { b1s[t] = b1[t]; g1s[t] = g1[t]; be1s[t] = be1[t]; }
    for (int i = t; i < 512; i += 256) w2s[i] = W2[i];
    if (t < 16) { b2s[t] = b2[t]; g2s[t] = g2[t]; be2s[t] = be2[t]; }
    __syncthreads();

    const int row = blockIdx.x * 256 + t;
    float4 v = *(const float4*)(xme + (size_t)row * 4);

    float h1v[32];
    float m = 0.f;
    #pragma unroll
    for (int i = 0; i < 32; i++) {
        float a = w1s[i*4+0]*v.x + w1s[i*4+1]*v.y + w1s[i*4+2]*v.z + w1s[i*4+3]*v.w + b1s[i];
        h1v[i] = a; m += a;
    }
    m *= (1.f / 32.f);
    float var = 0.f;
    #pragma unroll
    for (int i = 0; i < 32; i++) { float d = h1v[i] - m; var += d * d; }
    var *= (1.f / 32.f);
    float rs = rsqrtf(var + LN_EPSf);
    #pragma unroll
    for (int i = 0; i < 32; i++)
        h1v[i] = fmaxf((h1v[i] - m) * rs * g1s[i] + be1s[i], 0.f);

    float h2v[16];
    float m2 = 0.f;
    #pragma unroll
    for (int g = 0; g < 16; g++) {
        float a = b2s[g];
        #pragma unroll
        for (int i = 0; i < 32; i++) a = fmaf(w2s[g * 32 + i], h1v[i], a);
        h2v[g] = a; m2 += a;
    }
    m2 *= (1.f / 16.f);
    float v2 = 0.f;
    #pragma unroll
    for (int g = 0; g < 16; g++) { float d = h2v[g] - m2; v2 += d * d; }
    v2 *= (1.f / 16.f);
    float rs2 = rsqrtf(v2 + LN_EPSf);
    float* h2o = ws + WS_H2 + (size_t)row * 16;
    #pragma unroll
    for (int g = 0; g < 16; g++)
        h2o[g] = fmaxf((h2v[g] - m2) * rs2 * g2s[g] + be2s[g], 0.f);
}

// ---------------------------------------------------------------------------
// k_wcp (MFMA, 2-deep pipeline) + FUSED repack epilogue — unchanged, passing.
__global__ __launch_bounds__(256) void k_wcp(const float* __restrict__ Wc,
                                             const float* __restrict__ Wtp,
                                             float* __restrict__ ws)
{
    __shared__ __align__(16) unsigned short Bs[2][4][4][16][8];   // 8192 B
    const int pbase = blockIdx.x * 96;
    const int n0    = blockIdx.y * 64;
    const int t     = threadIdx.x;
    const int lane  = t & 63;
    const int wid   = t >> 6;
    const int wm    = wid >> 1;          // 0,1
    const int wn    = wid & 1;           // 0,1
    const int g8    = lane >> 4;         // 0..3  (k-group)
    const int n16   = lane & 15;

    const int bn  = t & 63;
    const int bkg = t >> 6;

    int prow[3];
    #pragma unroll
    for (int fi = 0; fi < 3; fi++) {
        int pr = pbase + wm * 48 + fi * 16 + n16;
        prow[fi] = pr < P ? pr : P - 1;
    }

#define LOADB_(dst, kt) {                                                   \
    const float* xs_ = Wc + (size_t)((kt) * 32 + 8 * bkg) * 3072 + n0 + bn; \
    _Pragma("unroll")                                                       \
    for (int e_ = 0; e_ < 8; e_++) dst[e_] = xs_[(size_t)e_ * 3072]; }

#define WRITEB_(src, buf) {                                                 \
    uint4 w_;                                                               \
    w_.x = f2bf(src[0]) | (f2bf(src[1]) << 16);                             \
    w_.y = f2bf(src[2]) | (f2bf(src[3]) << 16);                             \
    w_.z = f2bf(src[4]) | (f2bf(src[5]) << 16);                             \
    w_.w = f2bf(src[6]) | (f2bf(src[7]) << 16);                             \
    *(uint4*)&Bs[buf][bn >> 4][bkg][bn & 15][0] = w_; }

#define LOADA_(dst, kt) {                                                   \
    _Pragma("unroll")                                                       \
    for (int fi_ = 0; fi_ < 3; fi_++) {                                     \
        const float* as_ = Wtp + (size_t)prow[fi_] * 1024 + (kt) * 32 + g8 * 8; \
        dst[fi_][0] = *(const float4*)(as_);                                \
        dst[fi_][1] = *(const float4*)(as_ + 4); } }

#define PACKA_(fa, src) {                                                   \
    _Pragma("unroll")                                                       \
    for (int fi_ = 0; fi_ < 3; fi_++) {                                     \
        uint4 w_;                                                           \
        w_.x = f2bf(src[fi_][0].x) | (f2bf(src[fi_][0].y) << 16);           \
        w_.y = f2bf(src[fi_][0].z) | (f2bf(src[fi_][0].w) << 16);           \
        w_.z = f2bf(src[fi_][1].x) | (f2bf(src[fi_][1].y) << 16);           \
        w_.w = f2bf(src[fi_][1].z) | (f2bf(src[fi_][1].w) << 16);           \
        fa[fi_] = *(s16x8*)&w_; } }

#define MFMA6_(buf, fa) {                                                   \
    s16x8 fb0 = *(const s16x8*)&Bs[buf][2 * wn + 0][g8][n16][0];            \
    s16x8 fb1 = *(const s16x8*)&Bs[buf][2 * wn + 1][g8][n16][0];            \
    _Pragma("unroll")                                                       \
    for (int fi_ = 0; fi_ < 3; fi_++) {                                     \
        acc[fi_][0] = __builtin_amdgcn_mfma_f32_16x16x32_bf16(fa[fi_], fb0, acc[fi_][0], 0, 0, 0); \
        acc[fi_][1] = __builtin_amdgcn_mfma_f32_16x16x32_bf16(fa[fi_], fb1, acc[fi_][1], 0, 0, 0); } }

    f32x4 acc[3][2];
    #pragma unroll
    for (int i = 0; i < 3; i++) {
        acc[i][0] = (f32x4){0.f, 0.f, 0.f, 0.f};
        acc[i][1] = (f32x4){0.f, 0.f, 0.f, 0.f};
    }

    float  b0r[8], b1r[8];
    float4 a0r[3][2], a1r[3][2];

    LOADA_(a0r, 0); LOADB_(b0r, 0);
    LOADA_(a1r, 1); LOADB_(b1r, 1);
    WRITEB_(b0r, 0);
    __syncthreads();

    for (int i = 0; i < 16; i++) {
        const int kt = 2 * i;
        {
            s16x8 fa[3];
            PACKA_(fa, a0r);
            if (kt + 2 < 32) { LOADA_(a0r, kt + 2); LOADB_(b0r, kt + 2); }
            MFMA6_(0, fa);
        }
        __syncthreads();
        WRITEB_(b1r, 1);
        __syncthreads();
        {
            s16x8 fa[3];
            PACKA_(fa, a1r);
            if (kt + 3 < 32) { LOADA_(a1r, kt + 3); LOADB_(b1r, kt + 3); }
            MFMA6_(1, fa);
        }
        __syncthreads();
        if (kt + 2 < 32) WRITEB_(b0r, 0);
        __syncthreads();
    }

#undef LOADB_
#undef WRITEB_
#undef LOADA_
#undef PACKA_
#undef MFMA6_

    // ---- fused repack epilogue: value (p, m3=i*3+k) -> bf16 A-image ----
    unsigned short* aimg16 = (unsigned short*)(ws + WS_AIMG);
    #pragma unroll
    for (int fi = 0; fi < 3; fi++) {
        #pragma unroll
        for (int q = 0; q < 2; q++) {
            const int m3 = n0 + wn * 32 + q * 16 + n16;
            const int iq = m3 / 3;
            const int k  = m3 - 3 * iq;
            const int ch = k * 32 + (iq >> 5);
            const int lh = ((iq >> 3) & 3) << 4;
            const int e  = iq & 7;
            #pragma unroll
            for (int r = 0; r < 4; r++) {
                const int p  = pbase + wm * 48 + fi * 16 + g8 * 4 + r;
                const int pf = p >> 4;
                const int l  = lh | (p & 15);
                unsigned short v = (p < P) ? (unsigned short)f2bf(acc[fi][q][r])
                                           : (unsigned short)0;
                aimg16[((size_t)(ch * 24 + pf) * 64 + l) * 8 + e] = v;
            }
        }
    }
}

// ---------------------------------------------------------------------------
// k_mconv (MFMA, 4-deep A-prefetch) — unchanged, passing.
#define HT_RS 1056            /* u16 elems per row (2112 B) */
__global__ __launch_bounds__(256) void k_mconv(float* __restrict__ ws)
{
    __shared__ unsigned short Ht[18 * HT_RS];   // 38016 B
    const int b  = blockIdx.x;
    const int pt = blockIdx.y;                  // 0..5
    const int t  = threadIdx.x;
    const int l  = t & 63;
    const int wid = t >> 6;
    const int pf = pt * 4 + wid;                // 0..23
    const int n16 = l & 15;
    const int g8  = l >> 4;

    for (int j = t; j < HT_RS; j += 256) {
        Ht[j] = 0;
        Ht[17 * HT_RS + j] = 0;
    }
    {
        const float* h2b = ws + WS_H2 + (size_t)b * 16384;
        const int s0 = t * 4;
        float v[4][16];
        #pragma unroll
        for (int rr = 0; rr < 4; rr++) {
            const float4* src = (const float4*)(h2b + (size_t)(s0 + rr) * 16);
            float4 a0 = src[0], a1 = src[1], a2 = src[2], a3 = src[3];
            v[rr][0]=a0.x; v[rr][1]=a0.y; v[rr][2]=a0.z; v[rr][3]=a0.w;
            v[rr][4]=a1.x; v[rr][5]=a1.y; v[rr][6]=a1.z; v[rr][7]=a1.w;
            v[rr][8]=a2.x; v[rr][9]=a2.y; v[rr][10]=a2.z; v[rr][11]=a2.w;
            v[rr][12]=a3.x; v[rr][13]=a3.y; v[rr][14]=a3.z; v[rr][15]=a3.w;
        }
        #pragma unroll
        for (int g = 0; g < 16; g++) {
            uint2 w;
            w.x = f2bf(v[0][g]) | (f2bf(v[1][g]) << 16);
            w.y = f2bf(v[2][g]) | (f2bf(v[3][g]) << 16);
            *(uint2*)&Ht[(g + 1) * HT_RS + s0] = w;
        }
    }
    __syncthreads();

    const uint4* ab = (const uint4*)(ws + WS_AIMG);
    const size_t lidx = (size_t)pf * 64 + l;    // lane slot; stride 1536 u4/it
    f32x4 acc = (f32x4){0.f, 0.f, 0.f, 0.f};

    uint4 nf0 = ab[lidx + (size_t)0 * 1536];
    uint4 nf1 = ab[lidx + (size_t)1 * 1536];
    uint4 nf2 = ab[lidx + (size_t)2 * 1536];
    uint4 nf3 = ab[lidx + (size_t)3 * 1536];

    for (int g = 0; g < 24; g++) {
        uint4 c0 = nf0, c1 = nf1, c2 = nf2, c3 = nf3;
        if (g < 23) {
            const size_t nb = lidx + (size_t)(g + 1) * 4 * 1536;
            nf0 = ab[nb];
            nf1 = ab[nb + 1536];
            nf2 = ab[nb + 2 * 1536];
            nf3 = ab[nb + 3 * 1536];
        }
        #pragma unroll
        for (int e = 0; e < 4; e++) {
            const int it = 4 * g + e;
            const int k  = it >> 5;
            const int kt = it & 31;
            s16x8 fb = *(const s16x8*)&Ht[(n16 + k) * HT_RS + kt * 32 + g8 * 8];
            uint4 ce = (e == 0) ? c0 : (e == 1) ? c1 : (e == 2) ? c2 : c3;
            s16x8 fa = *(s16x8*)&ce;
            acc = __builtin_amdgcn_mfma_f32_16x16x32_bf16(fa, fb, acc, 0, 0, 0);
        }
    }

    #pragma unroll
    for (int r = 0; r < 4; r++) {
        int p = pf * 16 + g8 * 4 + r;
        if (p < P)
            ws[WS_M + ((size_t)b * P + p) * 16 + n16] = acc[r] + ws[WS_BCP + p];
    }
}

// ---------------------------------------------------------------------------
// k_pred (R14/R18 best-measured): MFMA bf16 GEMM + fused stats + fused
// epilogue. N-split: block = 192p x 64c, 256 threads (4 waves = 4M x 1N),
// grid (b, 4); counted-wait barrier (lgkmcnt-only + raw s_barrier).
#define P_BAR_() { asm volatile("s_waitcnt lgkmcnt(0)" ::: "memory");       \
                   __builtin_amdgcn_s_barrier(); }

__global__ __launch_bounds__(256, 2) void k_pred(
    const float* __restrict__ x,
    const float* __restrict__ W3, const float* __restrict__ b3,
    const float* __restrict__ ws, float* __restrict__ out)
{
    __shared__ __align__(16) unsigned short Bs[2][4][4][16][8];   // 8192 B
    __shared__ float sev[256], ssq[256], smean[64], sstd[64];
    const int b     = blockIdx.x;
    const int pt    = blockIdx.y;        // 0..3
    const int ptile = pt >> 1;           // 0,1 (192 p-rows each)
    const int chalf = pt & 1;            // 0,1 (64 c-cols each)
    const int t     = threadIdx.x;       // 0..255
    const int lane  = t & 63;
    const int wm    = t >> 6;            // 0..3 (4 M-waves)
    const int g8    = lane >> 4;         // 0..3  (k-group)
    const int n16   = lane & 15;

    const int sc  = t & 63;              // staging column (local)
    const int skg = t >> 6;              // staging k-group 0..3

    const float* xb = x + (size_t)b * S * C + chalf * 64;
    // A image: tile (kt*2 + ptile)*12288 B; sub = wm*3 + fi
    const char* aimgc = (const char*)ws + ptile * 12288
        + (wm * 3) * 1024 + g8 * 256 + n16 * 16;

    f32x4 acc[3][4];
    #pragma unroll
    for (int i = 0; i < 3; i++)
        #pragma unroll
        for (int j = 0; j < 4; j++) acc[i][j] = (f32x4){0.f, 0.f, 0.f, 0.f};

    float ev_acc = 0.f, sq_acc = 0.f;    // per-thread stats partials (col sc)

#define P_LOADB_(dst, kt) {                                                 \
    const float* xs_ = xb + (size_t)(32 * (kt) + 8 * skg) * C + sc;         \
    _Pragma("unroll")                                                       \
    for (int e_ = 0; e_ < 8; e_++) dst[e_] = xs_[(size_t)e_ * C]; }

#define P_WRITEB_(src, buf) {                                               \
    uint4 w_;                                                               \
    w_.x = f2bf(src[0]) | (f2bf(src[1]) << 16);                             \
    w_.y = f2bf(src[2]) | (f2bf(src[3]) << 16);                             \
    w_.z = f2bf(src[4]) | (f2bf(src[5]) << 16);                             \
    w_.w = f2bf(src[6]) | (f2bf(src[7]) << 16);                             \
    *(uint4*)&Bs[buf][sc >> 4][skg][sc & 15][0] = w_;                       \
    _Pragma("unroll")                                                       \
    for (int e_ = 0; e_ < 8; e_++) {                                        \
        float v_ = src[e_];                                                 \
        sq_acc = fmaf(v_, v_, sq_acc);                                      \
        if ((e_ & 1) == 0) ev_acc += v_;   /* s=32kt+8skg+e: even<=>e even */ \
    } }

#define P_LOADA_(dst, kt) {                                                 \
    const char* ap_ = aimgc + (size_t)(kt) * 24576;                         \
    _Pragma("unroll")                                                       \
    for (int fi_ = 0; fi_ < 3; fi_++)                                       \
        dst[fi_] = *(const uint4*)(ap_ + fi_ * 1024); }

#define P_MFMA_(buf, au) {                                                  \
    s16x8 fb0 = *(const s16x8*)&Bs[buf][0][g8][n16][0];                     \
    s16x8 fb1 = *(const s16x8*)&Bs[buf][1][g8][n16][0];                     \
    s16x8 fb2 = *(const s16x8*)&Bs[buf][2][g8][n16][0];                     \
    s16x8 fb3 = *(const s16x8*)&Bs[buf][3][g8][n16][0];                     \
    _Pragma("unroll")                                                       \
    for (int fi_ = 0; fi_ < 3; fi_++) {                                     \
        s16x8 fa_ = *(s16x8*)&au[fi_];                                      \
        acc[fi_][0] = __builtin_amdgcn_mfma_f32_16x16x32_bf16(fa_, fb0, acc[fi_][0], 0, 0, 0); \
        acc[fi_][1] = __builtin_amdgcn_mfma_f32_16x16x32_bf16(fa_, fb1, acc[fi_][1], 0, 0, 0); \
        acc[fi_][2] = __builtin_amdgcn_mfma_f32_16x16x32_bf16(fa_, fb2, acc[fi_][2], 0, 0, 0); \
        acc[fi_][3] = __builtin_amdgcn_mfma_f32_16x16x32_bf16(fa_, fb3, acc[fi_][3], 0, 0, 0); } }

    float b0r[8], b1r[8];     // R0 = even tiles, R1 = odd tiles
    uint4 a0u[3], a1u[3];

    // prologue: issue tiles 0,1; write tile 0 -> buf0
    P_LOADB_(b0r, 0); P_LOADB_(b1r, 1);
    P_LOADA_(a0u, 0); P_LOADA_(a1u, 1);
    P_WRITEB_(b0r, 0);
    P_BAR_();

    for (int i = 0; i < 16; i++) {
        const int kt = 2 * i;
        // even step kt: MFMA(buf0) || write tile kt+1 -> buf1
        {
            uint4 au[3];
            #pragma unroll
            for (int fi = 0; fi < 3; fi++) au[fi] = a0u[fi];   // A(kt), issued kt-2
            if (kt + 2 < 32) { P_LOADA_(a0u, kt + 2); P_LOADB_(b0r, kt + 2); }
            P_MFMA_(0, au);
            P_WRITEB_(b1r, 1);            // tile kt+1 (loads issued >=1 iter ago)
            P_BAR_();
        }
        // odd step kt+1: MFMA(buf1) || write tile kt+2 -> buf0
        {
            const int kt1 = kt + 1;
            uint4 au[3];
            #pragma unroll
            for (int fi = 0; fi < 3; fi++) au[fi] = a1u[fi];   // A(kt1)
            if (kt1 + 2 < 32) { P_LOADA_(a1u, kt1 + 2); P_LOADB_(b1r, kt1 + 2); }
            P_MFMA_(1, au);
            if (kt1 < 31) P_WRITEB_(b0r, 0);   // tile kt1+1
            P_BAR_();
        }
    }

#undef P_LOADB_
#undef P_WRITEB_
#undef P_LOADA_
#undef P_MFMA_

    // ---- in-block stats reduction (4 skg-groups share column sc) ----
    sev[t] = ev_acc; ssq[t] = sq_acc;
    __syncthreads();
    if (t < 64) {
        float ev = sev[t] + sev[t + 64] + sev[t + 128] + sev[t + 192];
        float sq = ssq[t] + ssq[t + 64] + ssq[t + 128] + ssq[t + 192];
        float mean = ev * (INV_SQRT2f / 512.f);
        float var  = (sq - 1024.f * mean * mean) * (1.f / 1023.f);  // ddof=1
        smean[t] = mean;
        sstd[t]  = sqrtf(var + LN_EPSf);
    }
    __syncthreads();

    // ---- epilogue ----
    float sdv[4], mnv[4], b3v[4];
    f32x4 w3r[4][4];
    #pragma unroll
    for (int fj = 0; fj < 4; fj++) {
        int cl = fj * 16 + n16;            // local col 0..63
        int c  = chalf * 64 + cl;          // global col
        sdv[fj] = sstd[cl];
        mnv[fj] = smean[cl];
        b3v[fj] = b3[c];
        const f32x4* wr = (const f32x4*)(W3 + c * 16);
        #pragma unroll
        for (int q = 0; q < 4; q++) w3r[fj][q] = wr[q];
    }
    const int prow0 = ptile * 192 + wm * 48 + g8 * 4;
    #pragma unroll
    for (int fi = 0; fi < 3; fi++) {
        #pragma unroll
        for (int r = 0; r < 4; r++) {
            int p  = prow0 + fi * 16 + r;
            int pc = p < P ? p : P - 1;
            const f32x4* mrow = (const f32x4*)(ws + WS_M + ((size_t)b * P + pc) * 16);
            f32x4 m0 = mrow[0], m1 = mrow[1], m2 = mrow[2], m3 = mrow[3];
            const float* e = ws + WS_EPI + pc * 4;
            float A13 = e[0], A4 = e[1], A2 = e[2];
            #pragma unroll
            for (int fj = 0; fj < 4; fj++) {
                float s = 0.f;
                #pragma unroll
                for (int q = 0; q < 4; q++) {
                    const f32x4 mv = (q==0)?m0:(q==1)?m1:(q==2)?m2:m3;
                    s = fmaf(mv.x, w3r[fj][q].x, s);
                    s = fmaf(mv.y, w3r[fj][q].y, s);
                    s = fmaf(mv.z, w3r[fj][q].z, s);
                    s = fmaf(mv.w, w3r[fj][q].w, s);
                }
                float res = acc[fi][fj][r]
                          + sdv[fj] * (OMBf * s + A13 + A4 * b3v[fj])
                          + A2 * mnv[fj];
                if (p < P)
                    out[((size_t)b * P + p) * C + chalf * 64 + fj * 16 + n16] = res;
            }
        }
    }
}

// ---------------------------------------------------------------------------
extern "C" void kernel_launch(void* const* d_in, const int* in_sizes, int n_in,
                              void* d_out, int out_size, void* d_ws, size_t ws_size,
                              hipStream_t stream)
{
    const float* x    = (const float*)d_in[0];
    const float* xme  = (const float*)d_in[1];
    const float* W1   = (const float*)d_in[4];
    const float* b1   = (const float*)d_in[5];
    const float* g1   = (const float*)d_in[6];
    const float* be1  = (const float*)d_in[7];
    const float* W2   = (const float*)d_in[8];
    const float* b2   = (const float*)d_in[9];
    const float* g2   = (const float*)d_in[10];
    const float* be2  = (const float*)d_in[11];
    const float* Wc   = (const float*)d_in[12];
    const float* bc   = (const float*)d_in[13];
    const float* W3   = (const float*)d_in[14];
    const float* b3   = (const float*)d_in[15];
    const float* Wtp  = (const float*)d_in[16];
    const float* btp  = (const float*)d_in[17];
    const float* Whp  = (const float*)d_in[18];
    const float* bhp  = (const float*)d_in[19];
    float* ws  = (float*)d_ws;
    float* out = (float*)d_out;

    k_prep  <<<dim3(P),      dim3(256), 0, stream>>>(Whp, Wtp, bc, bhp, btp, ws);
    k_mlp   <<<dim3(512),    dim3(256), 0, stream>>>(xme, W1, b1, g1, be1,
                                                     W2, b2, g2, be2, ws);
    k_wcp   <<<dim3(4, 48),  dim3(256), 0, stream>>>(Wc, Wtp, ws);
    k_mconv <<<dim3(B, 6),   dim3(256), 0, stream>>>(ws);
    k_pred  <<<dim3(B, 4),   dim3(256), 0, stream>>>(x, W3, b3, ws, out);
}